// Round 2
// baseline (2029.868 us; speedup 1.0000x reference)
//
#include <hip/hip_runtime.h>

#define LRELU(x) ((x) > 0.f ? (x) : 0.2f*(x))

static inline int cdiv(int a, int b) { return (a + b - 1) / b; }

// ---------------------------------------------------------------------------
// GEMM h = x[N,64] @ W[64,H*D]  + fused el/er = einsum(h, al/ar) per head.
// Block = H*D threads (one output feature each), NPB nodes per block.
// W columns are coalesced (thread f reads W[k*HD+f]); x rows broadcast via LDS.
// ---------------------------------------------------------------------------
template<int H, int D, int NPB>
__global__ void gemm_elr_kernel(const float* __restrict__ x, const float* __restrict__ W,
                                const float* __restrict__ al, const float* __restrict__ ar,
                                float* __restrict__ h, float* __restrict__ el,
                                float* __restrict__ er, int N) {
  constexpr int HD = H * D;
  constexpr int NW = HD / 64;   // waves per block
  constexpr int WPH = D / 64;   // waves per head
  __shared__ float xs[NPB][64];
  __shared__ float redL[NPB][NW], redR[NPB][NW];
  const int f = threadIdx.x;
  const int n0 = blockIdx.x * NPB;
  for (int i = f; i < NPB * 64; i += HD) {
    int ni = n0 + (i >> 6);
    xs[i >> 6][i & 63] = (ni < N) ? x[ni * 64 + (i & 63)] : 0.f;
  }
  __syncthreads();
  float acc[NPB];
#pragma unroll
  for (int i = 0; i < NPB; i++) acc[i] = 0.f;
#pragma unroll 8
  for (int k = 0; k < 64; k++) {
    float w = W[k * HD + f];
#pragma unroll
    for (int i = 0; i < NPB; i++) acc[i] += xs[i][k] * w;
  }
  const float alv = al[f], arv = ar[f];
#pragma unroll
  for (int i = 0; i < NPB; i++) {
    int n = n0 + i;
    if (n < N) h[(size_t)n * HD + f] = acc[i];
  }
  const int wave = f >> 6, lane = f & 63;
#pragma unroll
  for (int i = 0; i < NPB; i++) {
    float pl = acc[i] * alv, pr = acc[i] * arv;
#pragma unroll
    for (int off = 32; off >= 1; off >>= 1) {
      pl += __shfl_xor(pl, off);
      pr += __shfl_xor(pr, off);
    }
    if (lane == 0) { redL[i][wave] = pl; redR[i][wave] = pr; }
  }
  __syncthreads();
  if (f < NPB * H) {
    int i = f / H, hh = f - (f / H) * H;
    float sl = 0.f, sr = 0.f;
#pragma unroll
    for (int w2 = 0; w2 < WPH; w2++) { sl += redL[i][hh * WPH + w2]; sr += redR[i][hh * WPH + w2]; }
    int n = n0 + i;
    if (n < N) { el[n * H + hh] = sl; er[n * H + hh] = sr; }
  }
}

// ---------------------------------------------------------------------------
// Edge pass 1: ex = exp(leaky_relu(el[src]+er[dst])); den[dst] += ex.
// (max-subtraction skipped: |e| is O(1), exp is safe, alpha identical)
// ---------------------------------------------------------------------------
template<int H>
__global__ void edge_denom_kernel(const float* __restrict__ el, const float* __restrict__ er,
                                  const int* __restrict__ src, const int* __restrict__ dst,
                                  float* __restrict__ ex, float* __restrict__ den, int E) {
  int t = blockIdx.x * blockDim.x + threadIdx.x;
  if (t >= E * H) return;
  int e = t / H, hh = t - e * H;
  int s = src[e], d = dst[e];
  float v = el[s * H + hh] + er[d * H + hh];
  v = LRELU(v);
  float ev = expf(v);
  ex[t] = ev;
  atomicAdd(&den[d * H + hh], ev);
}

// ---------------------------------------------------------------------------
// Edge pass 2: out[dst] += (ex/den[dst]) * h[src].  One edge per block.
// ---------------------------------------------------------------------------
template<int H, int D>
__global__ void edge_aggr_kernel(const float* __restrict__ hsrc, const float* __restrict__ ex,
                                 const float* __restrict__ den, const int* __restrict__ src,
                                 const int* __restrict__ dst, float* __restrict__ out, int E) {
  constexpr int HD = H * D;
  int e = blockIdx.x;
  int f = threadIdx.x;
  int s = src[e], d = dst[e];
  int hh = f / D;
  float alpha = ex[(size_t)e * H + hh] / den[d * H + hh];
  atomicAdd(&out[(size_t)d * HD + f], alpha * hsrc[(size_t)s * HD + f]);
}

// out1 -> relu(out1 + b) summed over 10 heads -> h1sum[N,64]
__global__ void finish1_kernel(const float* __restrict__ out1, const float* __restrict__ b,
                               float* __restrict__ h1sum, int N) {
  int t = blockIdx.x * blockDim.x + threadIdx.x;
  if (t >= N * 64) return;
  int n = t >> 6, d = t & 63;
  float s = 0.f;
#pragma unroll
  for (int hh = 0; hh < 10; hh++) {
    float v = out1[(size_t)n * 640 + hh * 64 + d] + b[hh * 64 + d];
    s += v > 0.f ? v : 0.f;
  }
  h1sum[t] = s;
}

// out2 -> relu(out2 + b2) -> segment-max readout (relu>=0 so uint atomicMax works)
__global__ void finish2_kernel(const float* __restrict__ out2, const float* __restrict__ b,
                               const int* __restrict__ gid, float* __restrict__ readout,
                               int N, int colOff) {
  int t = blockIdx.x * blockDim.x + threadIdx.x;
  if (t >= N * 128) return;
  int n = t >> 7, f = t & 127;
  float v = out2[t] + b[f];
  v = v > 0.f ? v : 0.f;
  atomicMax((unsigned int*)&readout[gid[n] * 256 + colOff + f], __float_as_uint(v));
}

// MLP: relu(concat @ W1 + b1) @ W2 + b2 -> relu -> out[32]
__global__ void mlp_kernel(const float* __restrict__ readout, const float* __restrict__ W1,
                           const float* __restrict__ b1, const float* __restrict__ W2,
                           const float* __restrict__ b2, float* __restrict__ out) {
  int b = blockIdx.x;   // 32
  int j = threadIdx.x;  // 128
  __shared__ float rs[256];
  rs[j] = readout[b * 256 + j];
  rs[j + 128] = readout[b * 256 + 128 + j];
  __syncthreads();
  float acc = b1[j];
#pragma unroll 8
  for (int k = 0; k < 256; k++) acc += rs[k] * W1[k * 128 + j];
  acc = acc > 0.f ? acc : 0.f;
  float p = acc * W2[j];
#pragma unroll
  for (int off = 32; off >= 1; off >>= 1) p += __shfl_xor(p, off);
  __shared__ float wsum[2];
  if ((threadIdx.x & 63) == 0) wsum[threadIdx.x >> 6] = p;
  __syncthreads();
  if (threadIdx.x == 0) {
    float s = wsum[0] + wsum[1] + b2[0];
    out[b] = s > 0.f ? s : 0.f;
  }
}

// ---------------------------------------------------------------------------
struct WsPtrs {
  float *h1, *out1, *ex1, *h1sum, *h2, *out2;
  float *el1, *er1, *den1, *el2, *er2, *den2, *ex2, *readout;
};

static void run_branch(const float* x, const int* src, const int* dst, const int* gid,
                       const float* W1, const float* al1, const float* ar1, const float* b1,
                       const float* W2, const float* al2, const float* ar2, const float* b2,
                       int N, int E, int colOff, const WsPtrs& w, hipStream_t stream) {
  // ---- layer 1: 64 -> 10 heads x 64 ----
  hipMemsetAsync(w.out1, 0, (size_t)N * 640 * 4, stream);
  hipMemsetAsync(w.den1, 0, (size_t)N * 10 * 4, stream);
  gemm_elr_kernel<10, 64, 8><<<cdiv(N, 8), 640, 0, stream>>>(x, W1, al1, ar1, w.h1, w.el1, w.er1, N);
  edge_denom_kernel<10><<<cdiv(E * 10, 256), 256, 0, stream>>>(w.el1, w.er1, src, dst, w.ex1, w.den1, E);
  edge_aggr_kernel<10, 64><<<E, 640, 0, stream>>>(w.h1, w.ex1, w.den1, src, dst, w.out1, E);
  finish1_kernel<<<cdiv(N * 64, 256), 256, 0, stream>>>(w.out1, b1, w.h1sum, N);
  // ---- layer 2: 64 -> 1 head x 128 ----
  hipMemsetAsync(w.out2, 0, (size_t)N * 128 * 4, stream);
  hipMemsetAsync(w.den2, 0, (size_t)N * 4, stream);
  gemm_elr_kernel<1, 128, 8><<<cdiv(N, 8), 128, 0, stream>>>(w.h1sum, W2, al2, ar2, w.h2, w.el2, w.er2, N);
  edge_denom_kernel<1><<<cdiv(E, 256), 256, 0, stream>>>(w.el2, w.er2, src, dst, w.ex2, w.den2, E);
  edge_aggr_kernel<1, 128><<<E, 128, 0, stream>>>(w.h2, w.ex2, w.den2, src, dst, w.out2, E);
  finish2_kernel<<<cdiv(N * 128, 256), 256, 0, stream>>>(w.out2, b2, gid, w.readout, N, colOff);
}

extern "C" void kernel_launch(void* const* d_in, const int* in_sizes, int n_in,
                              void* d_out, int out_size, void* d_ws, size_t ws_size,
                              hipStream_t stream) {
  const float* x_lig = (const float*)d_in[0];
  const int* src_lig = (const int*)d_in[1];
  const int* dst_lig = (const int*)d_in[2];
  const int* gid_lig = (const int*)d_in[3];
  const float* x_rec = (const float*)d_in[4];
  const int* src_rec = (const int*)d_in[5];
  const int* dst_rec = (const int*)d_in[6];
  const int* gid_rec = (const int*)d_in[7];
  const float* W1l = (const float*)d_in[8];
  const float* al1l = (const float*)d_in[9];
  const float* ar1l = (const float*)d_in[10];
  const float* b1l = (const float*)d_in[11];
  const float* W2l = (const float*)d_in[12];
  const float* al2l = (const float*)d_in[13];
  const float* ar2l = (const float*)d_in[14];
  const float* b2l = (const float*)d_in[15];
  const float* W1r = (const float*)d_in[16];
  const float* al1r = (const float*)d_in[17];
  const float* ar1r = (const float*)d_in[18];
  const float* b1r = (const float*)d_in[19];
  const float* W2r = (const float*)d_in[20];
  const float* al2r = (const float*)d_in[21];
  const float* ar2r = (const float*)d_in[22];
  const float* b2r = (const float*)d_in[23];
  const float* W_lin1 = (const float*)d_in[24];
  const float* b_lin1 = (const float*)d_in[25];
  const float* W_lin2 = (const float*)d_in[26];
  const float* b_lin2 = (const float*)d_in[27];

  const int NMAX = 30000, EMAX = 480000;
  float* p = (float*)d_ws;
  WsPtrs w;
  w.h1 = p;            p += (size_t)NMAX * 640;
  w.out1 = p;          p += (size_t)NMAX * 640;
  w.ex1 = p;           p += (size_t)EMAX * 10;
  w.h1sum = p;         p += (size_t)NMAX * 64;
  w.h2 = p;            p += (size_t)NMAX * 128;
  w.out2 = p;          p += (size_t)NMAX * 128;
  w.el1 = p;           p += (size_t)NMAX * 10;
  w.er1 = p;           p += (size_t)NMAX * 10;
  w.den1 = p;          p += (size_t)NMAX * 10;
  w.el2 = p;           p += NMAX;
  w.er2 = p;           p += NMAX;
  w.den2 = p;          p += NMAX;
  w.ex2 = p;           p += EMAX;
  w.readout = p;       p += 32 * 256;

  hipMemsetAsync(w.readout, 0, 32 * 256 * 4, stream);

  run_branch(x_lig, src_lig, dst_lig, gid_lig, W1l, al1l, ar1l, b1l,
             W2l, al2l, ar2l, b2l, 10000, 80000, 0, w, stream);
  run_branch(x_rec, src_rec, dst_rec, gid_rec, W1r, al1r, ar1r, b1r,
             W2r, al2r, ar2r, b2r, 30000, 480000, 128, w, stream);

  mlp_kernel<<<32, 128, 0, stream>>>(w.readout, W_lin1, b_lin1, W_lin2, b_lin2, (float*)d_out);
}

// Round 3
// 947.526 us; speedup vs baseline: 2.1423x; 2.1423x over previous
//
#include <hip/hip_runtime.h>

#define LRELU(x) ((x) > 0.f ? (x) : 0.2f*(x))

static inline int cdiv(int a, int b) { return (a + b - 1) / b; }

// ---------------------------------------------------------------------------
// GEMM h = x[N,64] @ W[64,H*D]  + fused el/er = einsum(h, al/ar) per head.
// ---------------------------------------------------------------------------
template<int H, int D, int NPB>
__global__ void gemm_elr_kernel(const float* __restrict__ x, const float* __restrict__ W,
                                const float* __restrict__ al, const float* __restrict__ ar,
                                float* __restrict__ h, float* __restrict__ el,
                                float* __restrict__ er, int N) {
  constexpr int HD = H * D;
  constexpr int NW = HD / 64;   // waves per block
  constexpr int WPH = D / 64;   // waves per head
  __shared__ float xs[NPB][64];
  __shared__ float redL[NPB][NW], redR[NPB][NW];
  const int f = threadIdx.x;
  const int n0 = blockIdx.x * NPB;
  for (int i = f; i < NPB * 64; i += HD) {
    int ni = n0 + (i >> 6);
    xs[i >> 6][i & 63] = (ni < N) ? x[ni * 64 + (i & 63)] : 0.f;
  }
  __syncthreads();
  float acc[NPB];
#pragma unroll
  for (int i = 0; i < NPB; i++) acc[i] = 0.f;
#pragma unroll 8
  for (int k = 0; k < 64; k++) {
    float w = W[k * HD + f];
#pragma unroll
    for (int i = 0; i < NPB; i++) acc[i] += xs[i][k] * w;
  }
  const float alv = al[f], arv = ar[f];
#pragma unroll
  for (int i = 0; i < NPB; i++) {
    int n = n0 + i;
    if (n < N) h[(size_t)n * HD + f] = acc[i];
  }
  const int wave = f >> 6, lane = f & 63;
#pragma unroll
  for (int i = 0; i < NPB; i++) {
    float pl = acc[i] * alv, pr = acc[i] * arv;
#pragma unroll
    for (int off = 32; off >= 1; off >>= 1) {
      pl += __shfl_xor(pl, off);
      pr += __shfl_xor(pr, off);
    }
    if (lane == 0) { redL[i][wave] = pl; redR[i][wave] = pr; }
  }
  __syncthreads();
  if (f < NPB * H) {
    int i = f / H, hh = f - (f / H) * H;
    float sl = 0.f, sr = 0.f;
#pragma unroll
    for (int w2 = 0; w2 < WPH; w2++) { sl += redL[i][hh * WPH + w2]; sr += redR[i][hh * WPH + w2]; }
    int n = n0 + i;
    if (n < N) { el[n * H + hh] = sl; er[n * H + hh] = sr; }
  }
}

// ---------------------------------------------------------------------------
// CSR build: deg count -> exclusive scan (single block) -> scatter src ids
// ---------------------------------------------------------------------------
__global__ void deg_count_kernel(const int* __restrict__ dst, int* __restrict__ deg, int E) {
  int t = blockIdx.x * blockDim.x + threadIdx.x;
  if (t < E) atomicAdd(&deg[dst[t]], 1);
}

__global__ void scan_kernel(const int* __restrict__ deg, int* __restrict__ row_ptr,
                            int* __restrict__ cursor, int N) {
  __shared__ int wsum[16];
  __shared__ int woff[17];
  __shared__ int running;
  if (threadIdx.x == 0) running = 0;
  __syncthreads();
  for (int base = 0; base < N; base += 1024) {
    int i = base + (int)threadIdx.x;
    int v = (i < N) ? deg[i] : 0;
    int lane = threadIdx.x & 63, wv = threadIdx.x >> 6;
    int x = v;
#pragma unroll
    for (int off = 1; off < 64; off <<= 1) {
      int y = __shfl_up(x, off);
      if (lane >= off) x += y;
    }
    if (lane == 63) wsum[wv] = x;
    __syncthreads();
    if (threadIdx.x == 0) {
      int t = 0; woff[0] = 0;
      for (int w2 = 0; w2 < 16; w2++) { t += wsum[w2]; woff[w2 + 1] = t; }
    }
    __syncthreads();
    int excl = x - v + woff[wv] + running;
    if (i < N) { row_ptr[i] = excl; cursor[i] = excl; }
    __syncthreads();
    if (threadIdx.x == 0) running += woff[16];
    __syncthreads();
  }
  if (threadIdx.x == 0) row_ptr[N] = running;
}

__global__ void scatter_kernel(const int* __restrict__ src, const int* __restrict__ dst,
                               int* __restrict__ cursor, int* __restrict__ srcs, int E) {
  int t = blockIdx.x * blockDim.x + threadIdx.x;
  if (t >= E) return;
  int slot = atomicAdd(&cursor[dst[t]], 1);
  srcs[slot] = src[t];
}

// ---------------------------------------------------------------------------
// Layer-1 aggregation, gather form. Block = 640 threads = 10 head-waves, one
// block per dst node. Fuses: edge softmax (recomputed ex, deferred /den),
// bias, relu, head-sum. One write per (node, dim): h1sum[N,64].
// ---------------------------------------------------------------------------
__global__ void aggr_sumheads_kernel(const int* __restrict__ row_ptr, const int* __restrict__ srcs,
                                     const float* __restrict__ h, const float* __restrict__ el,
                                     const float* __restrict__ er, const float* __restrict__ b,
                                     float* __restrict__ h1sum, int N) {
  constexpr int H = 10;
  const int n = blockIdx.x;
  const int hh = threadIdx.x >> 6, lane = threadIdx.x & 63;
  const int beg = row_ptr[n], end = row_ptr[n + 1];
  const float ern = er[n * H + hh];
  float den = 0.f, acc = 0.f;
  int i = beg;
  for (; i + 1 < end; i += 2) {
    int s0 = srcs[i], s1 = srcs[i + 1];
    float e0 = el[s0 * H + hh] + ern;
    float e1 = el[s1 * H + hh] + ern;
    e0 = LRELU(e0); e1 = LRELU(e1);
    float x0 = expf(e0), x1 = expf(e1);
    float h0 = h[(size_t)s0 * 640 + hh * 64 + lane];
    float h1 = h[(size_t)s1 * 640 + hh * 64 + lane];
    den += x0 + x1;
    acc += x0 * h0 + x1 * h1;
  }
  if (i < end) {
    int s0 = srcs[i];
    float e0 = el[s0 * H + hh] + ern;
    e0 = LRELU(e0);
    float x0 = expf(e0);
    den += x0;
    acc += x0 * h[(size_t)s0 * 640 + hh * 64 + lane];
  }
  float v = (end > beg) ? acc / den : 0.f;
  v += b[hh * 64 + lane];
  v = v > 0.f ? v : 0.f;
  __shared__ float lds[H][64];
  lds[hh][lane] = v;
  __syncthreads();
  if (threadIdx.x < 64) {
    float s = 0.f;
#pragma unroll
    for (int k = 0; k < H; k++) s += lds[k][threadIdx.x];
    h1sum[(size_t)n * 64 + threadIdx.x] = s;
  }
}

// ---------------------------------------------------------------------------
// Layer-2 aggregation (H=1, D=128), gather form, one wave per node (2 feats
// per lane via float2). Fuses bias, relu, and segment-max readout.
// ---------------------------------------------------------------------------
__global__ void aggr2_readout_kernel(const int* __restrict__ row_ptr, const int* __restrict__ srcs,
                                     const float* __restrict__ h2, const float* __restrict__ el,
                                     const float* __restrict__ er, const float* __restrict__ b,
                                     const int* __restrict__ gid, float* __restrict__ readout,
                                     int N, int colOff) {
  const int wv = threadIdx.x >> 6, lane = threadIdx.x & 63;
  const int n = blockIdx.x * (blockDim.x >> 6) + wv;
  if (n >= N) return;
  const int beg = row_ptr[n], end = row_ptr[n + 1];
  const float ern = er[n];
  const float2* h2v = (const float2*)h2;
  float den = 0.f;
  float ax = 0.f, ay = 0.f;
  int i = beg;
  for (; i + 1 < end; i += 2) {
    int s0 = srcs[i], s1 = srcs[i + 1];
    float e0 = LRELU(el[s0] + ern), e1 = LRELU(el[s1] + ern);
    float x0 = expf(e0), x1 = expf(e1);
    float2 hv0 = h2v[(size_t)s0 * 64 + lane];
    float2 hv1 = h2v[(size_t)s1 * 64 + lane];
    den += x0 + x1;
    ax += x0 * hv0.x + x1 * hv1.x;
    ay += x0 * hv0.y + x1 * hv1.y;
  }
  if (i < end) {
    int s0 = srcs[i];
    float e0 = LRELU(el[s0] + ern);
    float x0 = expf(e0);
    float2 hv0 = h2v[(size_t)s0 * 64 + lane];
    den += x0;
    ax += x0 * hv0.x;
    ay += x0 * hv0.y;
  }
  float inv = (end > beg) ? 1.f / den : 0.f;
  float v0 = ax * inv + b[lane * 2];
  float v1 = ay * inv + b[lane * 2 + 1];
  v0 = v0 > 0.f ? v0 : 0.f;
  v1 = v1 > 0.f ? v1 : 0.f;
  int g = gid[n];
  atomicMax((unsigned int*)&readout[g * 256 + colOff + lane * 2], __float_as_uint(v0));
  atomicMax((unsigned int*)&readout[g * 256 + colOff + lane * 2 + 1], __float_as_uint(v1));
}

// MLP: relu(concat @ W1 + b1) @ W2 + b2 -> relu -> out[32]
__global__ void mlp_kernel(const float* __restrict__ readout, const float* __restrict__ W1,
                           const float* __restrict__ b1, const float* __restrict__ W2,
                           const float* __restrict__ b2, float* __restrict__ out) {
  int b = blockIdx.x;   // 32
  int j = threadIdx.x;  // 128
  __shared__ float rs[256];
  rs[j] = readout[b * 256 + j];
  rs[j + 128] = readout[b * 256 + 128 + j];
  __syncthreads();
  float acc = b1[j];
#pragma unroll 8
  for (int k = 0; k < 256; k++) acc += rs[k] * W1[k * 128 + j];
  acc = acc > 0.f ? acc : 0.f;
  float p = acc * W2[j];
#pragma unroll
  for (int off = 32; off >= 1; off >>= 1) p += __shfl_xor(p, off);
  __shared__ float wsum[2];
  if ((threadIdx.x & 63) == 0) wsum[threadIdx.x >> 6] = p;
  __syncthreads();
  if (threadIdx.x == 0) {
    float s = wsum[0] + wsum[1] + b2[0];
    out[b] = s > 0.f ? s : 0.f;
  }
}

// ---------------------------------------------------------------------------
struct WsPtrs {
  float *h1, *h1sum, *h2;
  float *el1, *er1, *el2, *er2, *readout;
  int *deg, *cursor, *srcs;   // deg doubles as row_ptr
};

static void run_branch(const float* x, const int* src, const int* dst, const int* gid,
                       const float* W1, const float* al1, const float* ar1, const float* b1,
                       const float* W2, const float* al2, const float* ar2, const float* b2,
                       int N, int E, int colOff, const WsPtrs& w, int* row_ptr,
                       hipStream_t stream) {
  // ---- CSR build (shared by both layers) ----
  hipMemsetAsync(w.deg, 0, (size_t)(N + 1) * 4, stream);
  deg_count_kernel<<<cdiv(E, 256), 256, 0, stream>>>(dst, w.deg, E);
  scan_kernel<<<1, 1024, 0, stream>>>(w.deg, row_ptr, w.cursor, N);
  scatter_kernel<<<cdiv(E, 256), 256, 0, stream>>>(src, dst, w.cursor, w.srcs, E);
  // ---- layer 1: 64 -> 10 heads x 64, relu, head-sum ----
  gemm_elr_kernel<10, 64, 8><<<cdiv(N, 8), 640, 0, stream>>>(x, W1, al1, ar1, w.h1, w.el1, w.er1, N);
  aggr_sumheads_kernel<<<N, 640, 0, stream>>>(row_ptr, w.srcs, w.h1, w.el1, w.er1, b1, w.h1sum, N);
  // ---- layer 2: 64 -> 1 head x 128, relu, segment-max readout ----
  gemm_elr_kernel<1, 128, 8><<<cdiv(N, 8), 128, 0, stream>>>(w.h1sum, W2, al2, ar2, w.h2, w.el2, w.er2, N);
  aggr2_readout_kernel<<<cdiv(N, 4), 256, 0, stream>>>(row_ptr, w.srcs, w.h2, w.el2, w.er2, b2,
                                                       gid, w.readout, N, colOff);
}

extern "C" void kernel_launch(void* const* d_in, const int* in_sizes, int n_in,
                              void* d_out, int out_size, void* d_ws, size_t ws_size,
                              hipStream_t stream) {
  const float* x_lig = (const float*)d_in[0];
  const int* src_lig = (const int*)d_in[1];
  const int* dst_lig = (const int*)d_in[2];
  const int* gid_lig = (const int*)d_in[3];
  const float* x_rec = (const float*)d_in[4];
  const int* src_rec = (const int*)d_in[5];
  const int* dst_rec = (const int*)d_in[6];
  const int* gid_rec = (const int*)d_in[7];
  const float* W1l = (const float*)d_in[8];
  const float* al1l = (const float*)d_in[9];
  const float* ar1l = (const float*)d_in[10];
  const float* b1l = (const float*)d_in[11];
  const float* W2l = (const float*)d_in[12];
  const float* al2l = (const float*)d_in[13];
  const float* ar2l = (const float*)d_in[14];
  const float* b2l = (const float*)d_in[15];
  const float* W1r = (const float*)d_in[16];
  const float* al1r = (const float*)d_in[17];
  const float* ar1r = (const float*)d_in[18];
  const float* b1r = (const float*)d_in[19];
  const float* W2r = (const float*)d_in[20];
  const float* al2r = (const float*)d_in[21];
  const float* ar2r = (const float*)d_in[22];
  const float* b2r = (const float*)d_in[23];
  const float* W_lin1 = (const float*)d_in[24];
  const float* b_lin1 = (const float*)d_in[25];
  const float* W_lin2 = (const float*)d_in[26];
  const float* b_lin2 = (const float*)d_in[27];

  const int NMAX = 30000, EMAX = 480000;
  float* p = (float*)d_ws;
  WsPtrs w;
  w.h1 = p;       p += (size_t)NMAX * 640;
  w.h1sum = p;    p += (size_t)NMAX * 64;
  w.h2 = p;       p += (size_t)NMAX * 128;
  w.el1 = p;      p += (size_t)NMAX * 10;
  w.er1 = p;      p += (size_t)NMAX * 10;
  w.el2 = p;      p += NMAX;
  w.er2 = p;      p += NMAX;
  w.readout = p;  p += 32 * 256;
  int* ip = (int*)p;
  w.deg = ip;     ip += NMAX + 1;       // also used as row_ptr output
  w.cursor = ip;  ip += NMAX;
  w.srcs = ip;    ip += EMAX;

  hipMemsetAsync(w.readout, 0, 32 * 256 * 4, stream);

  run_branch(x_lig, src_lig, dst_lig, gid_lig, W1l, al1l, ar1l, b1l,
             W2l, al2l, ar2l, b2l, 10000, 80000, 0, w, w.deg, stream);
  run_branch(x_rec, src_rec, dst_rec, gid_rec, W1r, al1r, ar1r, b1r,
             W2r, al2r, ar2r, b2r, 30000, 480000, 128, w, w.deg, stream);

  mlp_kernel<<<32, 128, 0, stream>>>(w.readout, W_lin1, b_lin1, W_lin2, b_lin2, (float*)d_out);
}

// Round 4
// 896.931 us; speedup vs baseline: 2.2631x; 1.0564x over previous
//
#include <hip/hip_runtime.h>

#define LRELU(x) ((x) > 0.f ? (x) : 0.2f*(x))

static inline int cdiv(int a, int b) { return (a + b - 1) / b; }

// ---------------------------------------------------------------------------
// A: wal[h][k] = sum_d W[k, h*DH+d] * al[h][d]   (and war with ar)
// One small block; H*64 threads, thread f = (h, k).
// ---------------------------------------------------------------------------
template<int H, int DH>
__global__ void prep_wal_kernel(const float* __restrict__ W, const float* __restrict__ al,
                                const float* __restrict__ ar, float* __restrict__ wal,
                                float* __restrict__ war) {
  constexpr int HD = H * DH;
  const int f = threadIdx.x;          // H*64
  const int h = f >> 6, k = f & 63;
  float sl = 0.f, sr = 0.f;
  for (int d = 0; d < DH; d++) {
    float w = W[k * HD + h * DH + d];
    sl += w * al[h * DH + d];
    sr += w * ar[h * DH + d];
  }
  wal[f] = sl;
  war[f] = sr;
}

// ---------------------------------------------------------------------------
// B: el[n,h] = x[n]·wal[h], er[n,h] = x[n]·war[h]. One wave per node.
// ---------------------------------------------------------------------------
template<int H>
__global__ void elr_kernel(const float* __restrict__ x, const float* __restrict__ wal,
                           const float* __restrict__ war, float* __restrict__ el,
                           float* __restrict__ er, int N) {
  const int wv = threadIdx.x >> 6, lane = threadIdx.x & 63;
  const int n = blockIdx.x * (blockDim.x >> 6) + wv;
  if (n >= N) return;
  const float xv = x[(size_t)n * 64 + lane];
#pragma unroll
  for (int h = 0; h < H; h++) {
    float pl = xv * wal[h * 64 + lane];
    float pr = xv * war[h * 64 + lane];
#pragma unroll
    for (int off = 32; off >= 1; off >>= 1) {
      pl += __shfl_xor(pl, off);
      pr += __shfl_xor(pr, off);
    }
    if (lane == 0) { el[(size_t)n * H + h] = pl; er[(size_t)n * H + h] = pr; }
  }
}

// ---------------------------------------------------------------------------
// CSR build: deg count -> exclusive scan (single block) -> scatter src ids
// ---------------------------------------------------------------------------
__global__ void deg_count_kernel(const int* __restrict__ dst, int* __restrict__ deg, int E) {
  int t = blockIdx.x * blockDim.x + threadIdx.x;
  if (t < E) atomicAdd(&deg[dst[t]], 1);
}

__global__ void scan_kernel(const int* __restrict__ deg, int* __restrict__ row_ptr,
                            int* __restrict__ cursor, int N) {
  __shared__ int wsum[16];
  __shared__ int woff[17];
  __shared__ int running;
  if (threadIdx.x == 0) running = 0;
  __syncthreads();
  for (int base = 0; base < N; base += 1024) {
    int i = base + (int)threadIdx.x;
    int v = (i < N) ? deg[i] : 0;
    int lane = threadIdx.x & 63, wv = threadIdx.x >> 6;
    int x = v;
#pragma unroll
    for (int off = 1; off < 64; off <<= 1) {
      int y = __shfl_up(x, off);
      if (lane >= off) x += y;
    }
    if (lane == 63) wsum[wv] = x;
    __syncthreads();
    if (threadIdx.x == 0) {
      int t = 0; woff[0] = 0;
      for (int w2 = 0; w2 < 16; w2++) { t += wsum[w2]; woff[w2 + 1] = t; }
    }
    __syncthreads();
    int excl = x - v + woff[wv] + running;
    if (i < N) { row_ptr[i] = excl; cursor[i] = excl; }
    __syncthreads();
    if (threadIdx.x == 0) running += woff[16];
    __syncthreads();
  }
  if (threadIdx.x == 0) row_ptr[N] = running;
}

__global__ void scatter_kernel(const int* __restrict__ src, const int* __restrict__ dst,
                               int* __restrict__ cursor, int* __restrict__ srcs, int E) {
  int t = blockIdx.x * blockDim.x + threadIdx.x;
  if (t >= E) return;
  int slot = atomicAdd(&cursor[dst[t]], 1);
  srcs[slot] = src[t];
}

// ---------------------------------------------------------------------------
// C (layer 1): z[n,h,:] = (sum_e alpha x[src_e]) / den  -- input-space aggr.
// Block per node, 640 threads = 10 head-waves; gather is the 64-dim x row
// (256 B/edge), shared across heads via L1.
// ---------------------------------------------------------------------------
__global__ void aggr_z10_kernel(const int* __restrict__ row_ptr, const int* __restrict__ srcs,
                                const float* __restrict__ x, const float* __restrict__ el,
                                const float* __restrict__ er, float* __restrict__ z, int N) {
  const int n = blockIdx.x;
  const int hh = threadIdx.x >> 6, lane = threadIdx.x & 63;
  const int beg = row_ptr[n], end = row_ptr[n + 1];
  const float ern = er[(size_t)n * 10 + hh];
  float den = 0.f, acc = 0.f;
  int i = beg;
  for (; i + 1 < end; i += 2) {
    int s0 = srcs[i], s1 = srcs[i + 1];
    float e0 = LRELU(el[(size_t)s0 * 10 + hh] + ern);
    float e1 = LRELU(el[(size_t)s1 * 10 + hh] + ern);
    float x0 = expf(e0), x1 = expf(e1);
    den += x0 + x1;
    acc += x0 * x[(size_t)s0 * 64 + lane] + x1 * x[(size_t)s1 * 64 + lane];
  }
  if (i < end) {
    int s0 = srcs[i];
    float x0 = expf(LRELU(el[(size_t)s0 * 10 + hh] + ern));
    den += x0;
    acc += x0 * x[(size_t)s0 * 64 + lane];
  }
  z[(size_t)n * 640 + hh * 64 + lane] = (end > beg) ? acc / den : 0.f;
}

// C (layer 2, H=1): z2[n,:64] over h1sum. One wave per node.
__global__ void aggr_z1_kernel(const int* __restrict__ row_ptr, const int* __restrict__ srcs,
                               const float* __restrict__ hin, const float* __restrict__ el,
                               const float* __restrict__ er, float* __restrict__ z, int N) {
  const int wv = threadIdx.x >> 6, lane = threadIdx.x & 63;
  const int n = blockIdx.x * (blockDim.x >> 6) + wv;
  if (n >= N) return;
  const int beg = row_ptr[n], end = row_ptr[n + 1];
  const float ern = er[n];
  float den = 0.f, acc = 0.f;
  int i = beg;
  for (; i + 1 < end; i += 2) {
    int s0 = srcs[i], s1 = srcs[i + 1];
    float x0 = expf(LRELU(el[s0] + ern));
    float x1 = expf(LRELU(el[s1] + ern));
    den += x0 + x1;
    acc += x0 * hin[(size_t)s0 * 64 + lane] + x1 * hin[(size_t)s1 * 64 + lane];
  }
  if (i < end) {
    int s0 = srcs[i];
    float x0 = expf(LRELU(el[s0] + ern));
    den += x0;
    acc += x0 * hin[(size_t)s0 * 64 + lane];
  }
  z[(size_t)n * 64 + lane] = (end > beg) ? acc / den : 0.f;
}

// ---------------------------------------------------------------------------
// D (layer 1): h1sum[n,d] = sum_h relu(z[n,h]@W_h + b[h,d]). NPB nodes/block,
// 640 threads, thread f = (h, d_out). zs reads broadcast within a wave.
// ---------------------------------------------------------------------------
template<int NPB>
__global__ void gemm_sumheads_kernel(const float* __restrict__ z, const float* __restrict__ W,
                                     const float* __restrict__ b, float* __restrict__ h1sum,
                                     int N) {
  __shared__ float zs[NPB][640];
  const int f = threadIdx.x;      // 640
  const int n0 = blockIdx.x * NPB;
#pragma unroll
  for (int i = 0; i < NPB; i++) {
    int n = n0 + i;
    zs[i][f] = (n < N) ? z[(size_t)n * 640 + f] : 0.f;
  }
  __syncthreads();
  float acc[NPB];
#pragma unroll
  for (int i = 0; i < NPB; i++) acc[i] = 0.f;
  const int hbase = f & ~63;      // h*64
#pragma unroll 8
  for (int k = 0; k < 64; k++) {
    float w = W[k * 640 + f];
#pragma unroll
    for (int i = 0; i < NPB; i++) acc[i] += zs[i][hbase + k] * w;
  }
  const float bb = b[f];
#pragma unroll
  for (int i = 0; i < NPB; i++) {
    float v = acc[i] + bb;
    acc[i] = v > 0.f ? v : 0.f;
  }
  for (int i = 0; i < NPB; i++) {
    __syncthreads();
    zs[0][f] = acc[i];
    __syncthreads();
    if (f < 64) {
      float s = 0.f;
#pragma unroll
      for (int h = 0; h < 10; h++) s += zs[0][h * 64 + f];
      int n = n0 + i;
      if (n < N) h1sum[(size_t)n * 64 + f] = s;
    }
  }
}

// ---------------------------------------------------------------------------
// D (layer 2): out2 = relu(z2@W2 + b2), fused segment-max readout.
// ---------------------------------------------------------------------------
template<int NPB>
__global__ void gemm2_readout_kernel(const float* __restrict__ z, const float* __restrict__ W,
                                     const float* __restrict__ b, const int* __restrict__ gid,
                                     float* __restrict__ readout, int N, int colOff) {
  __shared__ float zs[NPB][64];
  const int f = threadIdx.x;      // 128
  const int n0 = blockIdx.x * NPB;
  for (int idx = f; idx < NPB * 64; idx += 128) {
    int i = idx >> 6, k = idx & 63;
    int n = n0 + i;
    zs[i][k] = (n < N) ? z[(size_t)n * 64 + k] : 0.f;
  }
  __syncthreads();
  float acc[NPB];
#pragma unroll
  for (int i = 0; i < NPB; i++) acc[i] = 0.f;
#pragma unroll 8
  for (int k = 0; k < 64; k++) {
    float w = W[k * 128 + f];
#pragma unroll
    for (int i = 0; i < NPB; i++) acc[i] += zs[i][k] * w;
  }
  const float bb = b[f];
#pragma unroll
  for (int i = 0; i < NPB; i++) {
    int n = n0 + i;
    if (n < N) {
      float v = acc[i] + bb;
      v = v > 0.f ? v : 0.f;
      atomicMax((unsigned int*)&readout[gid[n] * 256 + colOff + f], __float_as_uint(v));
    }
  }
}

// MLP: relu(concat @ W1 + b1) @ W2 + b2 -> relu -> out[32]
__global__ void mlp_kernel(const float* __restrict__ readout, const float* __restrict__ W1,
                           const float* __restrict__ b1, const float* __restrict__ W2,
                           const float* __restrict__ b2, float* __restrict__ out) {
  int b = blockIdx.x;   // 32
  int j = threadIdx.x;  // 128
  __shared__ float rs[256];
  rs[j] = readout[b * 256 + j];
  rs[j + 128] = readout[b * 256 + 128 + j];
  __syncthreads();
  float acc = b1[j];
#pragma unroll 8
  for (int k = 0; k < 256; k++) acc += rs[k] * W1[k * 128 + j];
  acc = acc > 0.f ? acc : 0.f;
  float p = acc * W2[j];
#pragma unroll
  for (int off = 32; off >= 1; off >>= 1) p += __shfl_xor(p, off);
  __shared__ float wsum[2];
  if ((threadIdx.x & 63) == 0) wsum[threadIdx.x >> 6] = p;
  __syncthreads();
  if (threadIdx.x == 0) {
    float s = wsum[0] + wsum[1] + b2[0];
    out[b] = s > 0.f ? s : 0.f;
  }
}

// ---------------------------------------------------------------------------
struct WsPtrs {
  float *z, *z2, *h1sum;
  float *el1, *er1, *el2, *er2;
  float *wal1, *war1, *wal2, *war2, *readout;
  int *deg, *row_ptr, *cursor, *srcs;
};

static void run_branch(const float* x, const int* src, const int* dst, const int* gid,
                       const float* W1, const float* al1, const float* ar1, const float* b1,
                       const float* W2, const float* al2, const float* ar2, const float* b2,
                       int N, int E, int colOff, const WsPtrs& w, hipStream_t stream) {
  // ---- CSR build (shared by both layers) ----
  hipMemsetAsync(w.deg, 0, (size_t)N * 4, stream);
  deg_count_kernel<<<cdiv(E, 256), 256, 0, stream>>>(dst, w.deg, E);
  scan_kernel<<<1, 1024, 0, stream>>>(w.deg, w.row_ptr, w.cursor, N);
  scatter_kernel<<<cdiv(E, 256), 256, 0, stream>>>(src, dst, w.cursor, w.srcs, E);
  // ---- layer 1: 64 -> 10 heads x 64, relu, head-sum ----
  prep_wal_kernel<10, 64><<<1, 640, 0, stream>>>(W1, al1, ar1, w.wal1, w.war1);
  elr_kernel<10><<<cdiv(N, 4), 256, 0, stream>>>(x, w.wal1, w.war1, w.el1, w.er1, N);
  aggr_z10_kernel<<<N, 640, 0, stream>>>(w.row_ptr, w.srcs, x, w.el1, w.er1, w.z, N);
  gemm_sumheads_kernel<8><<<cdiv(N, 8), 640, 0, stream>>>(w.z, W1, b1, w.h1sum, N);
  // ---- layer 2: 64 -> 1 head x 128, relu, segment-max readout ----
  prep_wal_kernel<1, 128><<<1, 64, 0, stream>>>(W2, al2, ar2, w.wal2, w.war2);
  elr_kernel<1><<<cdiv(N, 4), 256, 0, stream>>>(w.h1sum, w.wal2, w.war2, w.el2, w.er2, N);
  aggr_z1_kernel<<<cdiv(N, 4), 256, 0, stream>>>(w.row_ptr, w.srcs, w.h1sum, w.el2, w.er2, w.z2, N);
  gemm2_readout_kernel<8><<<cdiv(N, 8), 128, 0, stream>>>(w.z2, W2, b2, gid, w.readout, N, colOff);
}

extern "C" void kernel_launch(void* const* d_in, const int* in_sizes, int n_in,
                              void* d_out, int out_size, void* d_ws, size_t ws_size,
                              hipStream_t stream) {
  const float* x_lig = (const float*)d_in[0];
  const int* src_lig = (const int*)d_in[1];
  const int* dst_lig = (const int*)d_in[2];
  const int* gid_lig = (const int*)d_in[3];
  const float* x_rec = (const float*)d_in[4];
  const int* src_rec = (const int*)d_in[5];
  const int* dst_rec = (const int*)d_in[6];
  const int* gid_rec = (const int*)d_in[7];
  const float* W1l = (const float*)d_in[8];
  const float* al1l = (const float*)d_in[9];
  const float* ar1l = (const float*)d_in[10];
  const float* b1l = (const float*)d_in[11];
  const float* W2l = (const float*)d_in[12];
  const float* al2l = (const float*)d_in[13];
  const float* ar2l = (const float*)d_in[14];
  const float* b2l = (const float*)d_in[15];
  const float* W1r = (const float*)d_in[16];
  const float* al1r = (const float*)d_in[17];
  const float* ar1r = (const float*)d_in[18];
  const float* b1r = (const float*)d_in[19];
  const float* W2r = (const float*)d_in[20];
  const float* al2r = (const float*)d_in[21];
  const float* ar2r = (const float*)d_in[22];
  const float* b2r = (const float*)d_in[23];
  const float* W_lin1 = (const float*)d_in[24];
  const float* b_lin1 = (const float*)d_in[25];
  const float* W_lin2 = (const float*)d_in[26];
  const float* b_lin2 = (const float*)d_in[27];

  const int NMAX = 30000, EMAX = 480000;
  float* p = (float*)d_ws;
  WsPtrs w;
  w.z = p;        p += (size_t)NMAX * 640;
  w.z2 = p;       p += (size_t)NMAX * 64;
  w.h1sum = p;    p += (size_t)NMAX * 64;
  w.el1 = p;      p += (size_t)NMAX * 10;
  w.er1 = p;      p += (size_t)NMAX * 10;
  w.el2 = p;      p += NMAX;
  w.er2 = p;      p += NMAX;
  w.wal1 = p;     p += 640;
  w.war1 = p;     p += 640;
  w.wal2 = p;     p += 64;
  w.war2 = p;     p += 64;
  w.readout = p;  p += 32 * 256;
  int* ip = (int*)p;
  w.deg = ip;     ip += NMAX;
  w.row_ptr = ip; ip += NMAX + 1;
  w.cursor = ip;  ip += NMAX;
  w.srcs = ip;    ip += EMAX;

  hipMemsetAsync(w.readout, 0, 32 * 256 * 4, stream);

  run_branch(x_lig, src_lig, dst_lig, gid_lig, W1l, al1l, ar1l, b1l,
             W2l, al2l, ar2l, b2l, 10000, 80000, 0, w, stream);
  run_branch(x_rec, src_rec, dst_rec, gid_rec, W1r, al1r, ar1r, b1r,
             W2r, al2r, ar2r, b2r, 30000, 480000, 128, w, stream);

  mlp_kernel<<<32, 128, 0, stream>>>(w.readout, W_lin1, b_lin1, W_lin2, b_lin2, (float*)d_out);
}

// Round 8
// 625.172 us; speedup vs baseline: 3.2469x; 1.4347x over previous
//
#include <hip/hip_runtime.h>

#define LRELU(x) fmaxf((x), 0.2f*(x))   // identical result to x>0?x:0.2x

static inline int cdiv(int a, int b) { return (a + b - 1) / b; }

// ---------------------------------------------------------------------------
// prep: wal[h*64+k] = sum_d W[k, h*DH+d] * al[h*DH+d]  (war likewise).
// One wave per output (h,k); lanes sweep d (coalesced).
// ---------------------------------------------------------------------------
template<int H, int DH>
__global__ void prep_wal_kernel(const float* __restrict__ W, const float* __restrict__ al,
                                const float* __restrict__ ar, float* __restrict__ wal,
                                float* __restrict__ war) {
  constexpr int K = 64;           // input dim
  constexpr int HD = H * DH;
  const int wv = threadIdx.x >> 6, lane = threadIdx.x & 63;
  const int o = blockIdx.x * (blockDim.x >> 6) + wv;   // output index in [0, H*K)
  if (o >= H * K) return;
  const int h = o / K, k = o - h * K;
  float pl = 0.f, pr = 0.f;
#pragma unroll
  for (int j = 0; j < DH / 64; j++) {
    int d = j * 64 + lane;
    float w = W[(size_t)k * HD + h * DH + d];
    pl += w * al[h * DH + d];
    pr += w * ar[h * DH + d];
  }
#pragma unroll
  for (int off = 32; off >= 1; off >>= 1) {
    pl += __shfl_xor(pl, off);
    pr += __shfl_xor(pr, off);
  }
  if (lane == 0) { wal[o] = pl; war[o] = pr; }
}

// ---------------------------------------------------------------------------
// el[n,h] = x[n]·wal[h], er[n,h] = x[n]·war[h]. One wave per node. (layer 1)
// ---------------------------------------------------------------------------
__global__ void elr10_kernel(const float* __restrict__ x, const float* __restrict__ wal,
                             const float* __restrict__ war, float* __restrict__ el,
                             float* __restrict__ er, int N) {
  const int wv = threadIdx.x >> 6, lane = threadIdx.x & 63;
  const int n = blockIdx.x * (blockDim.x >> 6) + wv;
  if (n >= N) return;
  const float xv = x[(size_t)n * 64 + lane];
#pragma unroll
  for (int h = 0; h < 10; h++) {
    float pl = xv * wal[h * 64 + lane];
    float pr = xv * war[h * 64 + lane];
#pragma unroll
    for (int off = 32; off >= 1; off >>= 1) {
      pl += __shfl_xor(pl, off);
      pr += __shfl_xor(pr, off);
    }
    if (lane == 0) { el[(size_t)n * 10 + h] = pl; er[(size_t)n * 10 + h] = pr; }
  }
}

// ---------------------------------------------------------------------------
// CSR build: deg count -> wave-atomic row offsets (order-free CSR) -> scatter
// ---------------------------------------------------------------------------
__global__ void deg_count_kernel(const int* __restrict__ dst, int* __restrict__ deg, int E) {
  int t = blockIdx.x * blockDim.x + threadIdx.x;
  if (t < E) atomicAdd(&deg[dst[t]], 1);
}

// row_ptr[n] = slice start (arbitrary order); cursor=row_ptr copy. counter pre-zeroed.
__global__ void rowptr_kernel(const int* __restrict__ deg, int* __restrict__ row_ptr,
                              int* __restrict__ cursor, int* __restrict__ counter, int N) {
  int t = blockIdx.x * blockDim.x + threadIdx.x;
  int lane = threadIdx.x & 63;
  int v = (t < N) ? deg[t] : 0;
  int x = v;
#pragma unroll
  for (int off = 1; off < 64; off <<= 1) {
    int y = __shfl_up(x, off);
    if (lane >= off) x += y;
  }
  int total = __shfl(x, 63);
  int base = 0;
  if (lane == 0 && total > 0) base = atomicAdd(counter, total);
  base = __shfl(base, 0);
  int excl = base + x - v;
  if (t < N) { row_ptr[t] = excl; cursor[t] = excl; }
}

__global__ void scatter_kernel(const int* __restrict__ src, const int* __restrict__ dst,
                               int* __restrict__ cursor, int* __restrict__ srcs, int E) {
  int t = blockIdx.x * blockDim.x + threadIdx.x;
  if (t >= E) return;
  int slot = atomicAdd(&cursor[dst[t]], 1);
  srcs[slot] = src[t];
}

// ---------------------------------------------------------------------------
// Layer-1 aggregation: ONE WAVE per node, all 10 heads in registers.
// Per edge: 1 x-row load (coalesced) + 5 float2 el-row loads + 10 exp/fma.
// ---------------------------------------------------------------------------
__global__ void aggr_z10_kernel(const int* __restrict__ row_ptr, const int* __restrict__ deg,
                                const int* __restrict__ srcs, const float* __restrict__ x,
                                const float* __restrict__ el, const float* __restrict__ er,
                                float* __restrict__ z, int N) {
  const int wv = threadIdx.x >> 6, lane = threadIdx.x & 63;
  const int n = blockIdx.x * (blockDim.x >> 6) + wv;
  if (n >= N) return;
  const int beg = row_ptr[n], dg = deg[n];
  const float2* elv = (const float2*)el;
  const float2* erv = (const float2*)er;
  float ern[10];
#pragma unroll
  for (int j = 0; j < 5; j++) {
    float2 t2 = erv[(size_t)n * 5 + j];
    ern[2 * j] = t2.x; ern[2 * j + 1] = t2.y;
  }
  float den[10], acc[10];
#pragma unroll
  for (int h = 0; h < 10; h++) { den[h] = 0.f; acc[h] = 0.f; }
  int i = 0;
  for (; i + 1 < dg; i += 2) {
    int s0 = srcs[beg + i], s1 = srcs[beg + i + 1];
    float xv0 = x[(size_t)s0 * 64 + lane];
    float xv1 = x[(size_t)s1 * 64 + lane];
    float w0[10], w1[10];
#pragma unroll
    for (int j = 0; j < 5; j++) {
      float2 a = elv[(size_t)s0 * 5 + j];
      float2 c = elv[(size_t)s1 * 5 + j];
      w0[2 * j] = a.x; w0[2 * j + 1] = a.y;
      w1[2 * j] = c.x; w1[2 * j + 1] = c.y;
    }
#pragma unroll
    for (int h = 0; h < 10; h++) {
      float ea = __expf(LRELU(w0[h] + ern[h]));
      float eb = __expf(LRELU(w1[h] + ern[h]));
      den[h] += ea + eb;
      acc[h] += ea * xv0 + eb * xv1;
    }
  }
  if (i < dg) {
    int s0 = srcs[beg + i];
    float xv0 = x[(size_t)s0 * 64 + lane];
    float w0[10];
#pragma unroll
    for (int j = 0; j < 5; j++) {
      float2 a = elv[(size_t)s0 * 5 + j];
      w0[2 * j] = a.x; w0[2 * j + 1] = a.y;
    }
#pragma unroll
    for (int h = 0; h < 10; h++) {
      float ea = __expf(LRELU(w0[h] + ern[h]));
      den[h] += ea;
      acc[h] += ea * xv0;
    }
  }
#pragma unroll
  for (int h = 0; h < 10; h++)
    z[(size_t)n * 640 + h * 64 + lane] = (dg > 0) ? acc[h] / den[h] : 0.f;
}

// ---------------------------------------------------------------------------
// Layer-2 aggregation (H=1): one wave per node over h1sum (64-dim).
// ---------------------------------------------------------------------------
__global__ void aggr_z1_kernel(const int* __restrict__ row_ptr, const int* __restrict__ deg,
                               const int* __restrict__ srcs, const float* __restrict__ hin,
                               const float* __restrict__ el, const float* __restrict__ er,
                               float* __restrict__ z, int N) {
  const int wv = threadIdx.x >> 6, lane = threadIdx.x & 63;
  const int n = blockIdx.x * (blockDim.x >> 6) + wv;
  if (n >= N) return;
  const int beg = row_ptr[n], dg = deg[n];
  const float ern = er[n];
  float den = 0.f, acc = 0.f;
  int i = 0;
  for (; i + 1 < dg; i += 2) {
    int s0 = srcs[beg + i], s1 = srcs[beg + i + 1];
    float x0 = __expf(LRELU(el[s0] + ern));
    float x1 = __expf(LRELU(el[s1] + ern));
    den += x0 + x1;
    acc += x0 * hin[(size_t)s0 * 64 + lane] + x1 * hin[(size_t)s1 * 64 + lane];
  }
  if (i < dg) {
    int s0 = srcs[beg + i];
    float x0 = __expf(LRELU(el[s0] + ern));
    den += x0;
    acc += x0 * hin[(size_t)s0 * 64 + lane];
  }
  z[(size_t)n * 64 + lane] = (dg > 0) ? acc / den : 0.f;
}

// ---------------------------------------------------------------------------
// Layer-1 GEMM + relu + head-sum; FUSED el2/er2 = h1sum·wal2/war2 epilogue.
// 640 threads, NPB nodes/block, 3 barriers total.
// ---------------------------------------------------------------------------
template<int NPB>
__global__ void gemm_sumheads_kernel(const float* __restrict__ z, const float* __restrict__ W,
                                     const float* __restrict__ b, const float* __restrict__ wal2,
                                     const float* __restrict__ war2, float* __restrict__ h1sum,
                                     float* __restrict__ el2, float* __restrict__ er2, int N) {
  __shared__ float zs[NPB][640];
  const int f = threadIdx.x;      // 640
  const int n0 = blockIdx.x * NPB;
#pragma unroll
  for (int i = 0; i < NPB; i++) {
    int n = n0 + i;
    zs[i][f] = (n < N) ? z[(size_t)n * 640 + f] : 0.f;
  }
  __syncthreads();
  float acc[NPB];
#pragma unroll
  for (int i = 0; i < NPB; i++) acc[i] = 0.f;
  const int hbase = f & ~63;      // h*64
#pragma unroll 8
  for (int k = 0; k < 64; k++) {
    float w = W[k * 640 + f];
#pragma unroll
    for (int i = 0; i < NPB; i++) acc[i] += zs[i][hbase + k] * w;
  }
  const float bb = b[f];
  __syncthreads();
#pragma unroll
  for (int i = 0; i < NPB; i++) zs[i][f] = fmaxf(acc[i] + bb, 0.f);
  __syncthreads();
  if (f < NPB * 64) {
    const int i = f >> 6, d = f & 63;      // wave i == node i (64-aligned)
    float s = 0.f;
#pragma unroll
    for (int h = 0; h < 10; h++) s += zs[i][h * 64 + d];
    const int n = n0 + i;
    if (n < N) h1sum[(size_t)n * 64 + d] = s;
    float pl = s * wal2[d], pr = s * war2[d];
#pragma unroll
    for (int off = 32; off >= 1; off >>= 1) {
      pl += __shfl_xor(pl, off);
      pr += __shfl_xor(pr, off);
    }
    if (d == 0 && n < N) { el2[n] = pl; er2[n] = pr; }
  }
}

// ---------------------------------------------------------------------------
// Layer-2 GEMM + relu + fused segment-max readout.
// ---------------------------------------------------------------------------
template<int NPB>
__global__ void gemm2_readout_kernel(const float* __restrict__ z, const float* __restrict__ W,
                                     const float* __restrict__ b, const int* __restrict__ gid,
                                     float* __restrict__ readout, int N, int colOff) {
  __shared__ float zs[NPB][64];
  const int f = threadIdx.x;      // 128
  const int n0 = blockIdx.x * NPB;
  for (int idx = f; idx < NPB * 64; idx += 128) {
    int i = idx >> 6, k = idx & 63;
    int n = n0 + i;
    zs[i][k] = (n < N) ? z[(size_t)n * 64 + k] : 0.f;
  }
  __syncthreads();
  float acc[NPB];
#pragma unroll
  for (int i = 0; i < NPB; i++) acc[i] = 0.f;
#pragma unroll 8
  for (int k = 0; k < 64; k++) {
    float w = W[k * 128 + f];
#pragma unroll
    for (int i = 0; i < NPB; i++) acc[i] += zs[i][k] * w;
  }
  const float bb = b[f];
#pragma unroll
  for (int i = 0; i < NPB; i++) {
    int n = n0 + i;
    if (n < N) {
      float v = fmaxf(acc[i] + bb, 0.f);
      atomicMax((unsigned int*)&readout[gid[n] * 256 + colOff + f], __float_as_uint(v));
    }
  }
}

// MLP: relu(concat @ W1 + b1) @ W2 + b2 -> relu -> out[32]
__global__ void mlp_kernel(const float* __restrict__ readout, const float* __restrict__ W1,
                           const float* __restrict__ b1, const float* __restrict__ W2,
                           const float* __restrict__ b2, float* __restrict__ out) {
  int b = blockIdx.x;   // 32
  int j = threadIdx.x;  // 128
  __shared__ float rs[256];
  rs[j] = readout[b * 256 + j];
  rs[j + 128] = readout[b * 256 + 128 + j];
  __syncthreads();
  float acc = b1[j];
#pragma unroll 8
  for (int k = 0; k < 256; k++) acc += rs[k] * W1[k * 128 + j];
  acc = fmaxf(acc, 0.f);
  float p = acc * W2[j];
#pragma unroll
  for (int off = 32; off >= 1; off >>= 1) p += __shfl_xor(p, off);
  __shared__ float wsum[2];
  if ((threadIdx.x & 63) == 0) wsum[threadIdx.x >> 6] = p;
  __syncthreads();
  if (threadIdx.x == 0) {
    float s = wsum[0] + wsum[1] + b2[0];
    out[b] = fmaxf(s, 0.f);
  }
}

// ---------------------------------------------------------------------------
struct WsPtrs {
  float *z, *z2, *h1sum;
  float *el1, *er1, *el2, *er2;
  float *wal1, *war1, *wal2, *war2, *readout;
  int *row_ptr, *cursor, *srcs;
};

static void run_branch(const float* x, const int* src, const int* dst, const int* gid,
                       const float* W1, const float* b1, const float* W2, const float* b2,
                       const float* wal1, const float* war1,
                       int N, int E, int colOff, const WsPtrs& w, int* deg, int* counter,
                       hipStream_t stream) {
  // ---- CSR build (deg/counter pre-zeroed by the upfront memset) ----
  deg_count_kernel<<<cdiv(E, 256), 256, 0, stream>>>(dst, deg, E);
  rowptr_kernel<<<cdiv(N, 256), 256, 0, stream>>>(deg, w.row_ptr, w.cursor, counter, N);
  scatter_kernel<<<cdiv(E, 256), 256, 0, stream>>>(src, dst, w.cursor, w.srcs, E);
  // ---- layer 1 ----
  elr10_kernel<<<cdiv(N, 4), 256, 0, stream>>>(x, wal1, war1, w.el1, w.er1, N);
  aggr_z10_kernel<<<cdiv(N, 8), 512, 0, stream>>>(w.row_ptr, deg, w.srcs, x, w.el1, w.er1, w.z, N);
  gemm_sumheads_kernel<8><<<cdiv(N, 8), 640, 0, stream>>>(w.z, W1, b1, w.wal2, w.war2,
                                                          w.h1sum, w.el2, w.er2, N);
  // ---- layer 2 ----
  aggr_z1_kernel<<<cdiv(N, 8), 512, 0, stream>>>(w.row_ptr, deg, w.srcs, w.h1sum, w.el2, w.er2,
                                                 w.z2, N);
  gemm2_readout_kernel<8><<<cdiv(N, 8), 128, 0, stream>>>(w.z2, W2, b2, gid, w.readout, N, colOff);
}

extern "C" void kernel_launch(void* const* d_in, const int* in_sizes, int n_in,
                              void* d_out, int out_size, void* d_ws, size_t ws_size,
                              hipStream_t stream) {
  const float* x_lig = (const float*)d_in[0];
  const int* src_lig = (const int*)d_in[1];
  const int* dst_lig = (const int*)d_in[2];
  const int* gid_lig = (const int*)d_in[3];
  const float* x_rec = (const float*)d_in[4];
  const int* src_rec = (const int*)d_in[5];
  const int* dst_rec = (const int*)d_in[6];
  const int* gid_rec = (const int*)d_in[7];
  const float* W1l = (const float*)d_in[8];
  const float* al1l = (const float*)d_in[9];
  const float* ar1l = (const float*)d_in[10];
  const float* b1l = (const float*)d_in[11];
  const float* W2l = (const float*)d_in[12];
  const float* al2l = (const float*)d_in[13];
  const float* ar2l = (const float*)d_in[14];
  const float* b2l = (const float*)d_in[15];
  const float* W1r = (const float*)d_in[16];
  const float* al1r = (const float*)d_in[17];
  const float* ar1r = (const float*)d_in[18];
  const float* b1r = (const float*)d_in[19];
  const float* W2r = (const float*)d_in[20];
  const float* al2r = (const float*)d_in[21];
  const float* ar2r = (const float*)d_in[22];
  const float* b2r = (const float*)d_in[23];
  const float* W_lin1 = (const float*)d_in[24];
  const float* b_lin1 = (const float*)d_in[25];
  const float* W_lin2 = (const float*)d_in[26];
  const float* b_lin2 = (const float*)d_in[27];

  const int NL = 10000, EL = 80000, NR = 30000, ER = 480000;
  const int NMAX = NR, EMAX = ER;
  float* p = (float*)d_ws;
  WsPtrs w;
  float *wal1l, *war1l, *wal1r, *war1r, *wal2l, *war2l, *wal2r, *war2r;
  w.z = p;        p += (size_t)NMAX * 640;
  w.z2 = p;       p += (size_t)NMAX * 64;
  w.h1sum = p;    p += (size_t)NMAX * 64;
  w.el1 = p;      p += (size_t)NMAX * 10;
  w.er1 = p;      p += (size_t)NMAX * 10;
  w.el2 = p;      p += NMAX;
  w.er2 = p;      p += NMAX;
  wal1l = p;      p += 640;
  war1l = p;      p += 640;
  wal1r = p;      p += 640;
  war1r = p;      p += 640;
  wal2l = p;      p += 64;
  war2l = p;      p += 64;
  wal2r = p;      p += 64;
  war2r = p;      p += 64;
  // ---- zeroed region: readout + degL + counterL + degR + counterR ----
  float* zero_base = p;
  w.readout = p;  p += 32 * 256;
  int* ip = (int*)p;
  int* degL = ip;     ip += NL;
  int* cntL = ip;     ip += 1;
  int* degR = ip;     ip += NR;
  int* cntR = ip;     ip += 1;
  size_t zero_bytes = (size_t)((char*)ip - (char*)zero_base);
  // ---- non-zeroed CSR scratch ----
  w.row_ptr = ip; ip += NMAX;
  w.cursor = ip;  ip += NMAX;
  w.srcs = ip;    ip += EMAX;

  hipMemsetAsync(zero_base, 0, zero_bytes, stream);

  // all four prep kernels are input-only; run upfront
  prep_wal_kernel<10, 64><<<80, 512, 0, stream>>>(W1l, al1l, ar1l, wal1l, war1l);
  prep_wal_kernel<1, 128><<<8, 512, 0, stream>>>(W2l, al2l, ar2l, wal2l, war2l);
  prep_wal_kernel<10, 64><<<80, 512, 0, stream>>>(W1r, al1r, ar1r, wal1r, war1r);
  prep_wal_kernel<1, 128><<<8, 512, 0, stream>>>(W2r, al2r, ar2r, wal2r, war2r);

  w.wal1 = wal1l; w.war1 = war1l; w.wal2 = wal2l; w.war2 = war2l;
  run_branch(x_lig, src_lig, dst_lig, gid_lig, W1l, b1l, W2l, b2l, wal1l, war1l,
             NL, EL, 0, w, degL, cntL, stream);
  w.wal1 = wal1r; w.war1 = war1r; w.wal2 = wal2r; w.war2 = war2r;
  run_branch(x_rec, src_rec, dst_rec, gid_rec, W1r, b1r, W2r, b2r, wal1r, war1r,
             NR, ER, 128, w, degR, cntR, stream);

  mlp_kernel<<<32, 128, 0, stream>>>(w.readout, W_lin1, b_lin1, W_lin2, b_lin2, (float*)d_out);
}